// Round 18
// baseline (954.597 us; speedup 1.0000x reference)
//
#include <hip/hip_runtime.h>
#include <hip/hip_bf16.h>
#include <math.h>

#define T_STEPS 12
#define NNODES  20000
#define NEDGES  320000
#define MPAD    20032
#define FIN     128
#define HG      256
#define RS_STRIDE 20032
#define CHK     16
#define HALF    10000

typedef unsigned short u16;
typedef unsigned int   u32;
typedef unsigned char  u8;
typedef unsigned long long u64;
using bf16x8 = __attribute__((ext_vector_type(8))) short;
using f32x4  = __attribute__((ext_vector_type(4))) float;
typedef float v2f __attribute__((ext_vector_type(2)));

__device__ __forceinline__ float bf2f(u16 u) {
    union { u32 i; float f; } v; v.i = ((u32)u) << 16; return v.f;
}
__device__ __forceinline__ u16 f2bf(float f) {
    union { float f; u32 i; } v; v.f = f;
    u32 r = v.i + 0x7fffu + ((v.i >> 16) & 1u);
    return (u16)(r >> 16);
}
__device__ __forceinline__ u16 f2h(float f) {
    _Float16 h = (_Float16)f; u16 u; __builtin_memcpy(&u, &h, 2); return u;
}
__device__ __forceinline__ float h2f(u16 u) {
    _Float16 h; __builtin_memcpy(&h, &u, 2); return (float)h;
}
__device__ __forceinline__ void gload16(const void* g, void* l) {
    __builtin_amdgcn_global_load_lds(
        (const __attribute__((address_space(1))) u32*)g,
        (__attribute__((address_space(3))) u32*)l, 16, 0, 0);
}
__device__ __forceinline__ float sigm(float x) { return 1.f / (1.f + expf(-x)); }

// ---------------- CSR build: rank-based counting sort (verified R16/R17) ----------------

__global__ void __launch_bounds__(1024) hist2(const int* __restrict__ edges,
        u8* __restrict__ rank, u8* __restrict__ counts) {
    __shared__ u32 lh[HALF];
    int c = blockIdx.x & 15;
    int rest = blockIdx.x >> 4;
    int s = rest & 1, t = rest >> 1;
    for (int i = threadIdx.x; i < HALF; i += 1024) lh[i] = 0;
    __syncthreads();
    int lo = s * HALF;
    const int* db = edges + (size_t)t * 2 * NEDGES + NEDGES;
    u8* rk = rank + (size_t)t * NEDGES;
    int per = NEDGES / CHK;
    int e0 = c * per, e1 = e0 + per;
    for (int i = e0 + (int)threadIdx.x; i < e1; i += 1024) {
        int d = db[i] - lo;
        if ((unsigned)d < HALF) {
            u32 r = atomicAdd(&lh[d], 1u);
            rk[i] = (u8)r;
        }
    }
    __syncthreads();
    u8* cnt = counts + (((size_t)(t * 2 + s) * CHK + c) * HALF);
    for (int i = threadIdx.x; i < HALF; i += 1024) cnt[i] = (u8)lh[i];
}

__global__ void __launch_bounds__(1024) scan2(const u8* __restrict__ counts,
        int* __restrict__ rowstart, float* __restrict__ dinv,
        int* __restrict__ chunkoff) {
    int t = blockIdx.x;
    int tid = threadIdx.x;
    int wid = tid >> 6, lane = tid & 63;
    __shared__ int wsum[16];
    __shared__ int carry_s;
    if (tid == 0) carry_s = 0;
    __syncthreads();
    for (int base = 0; base < NNODES; base += 1024) {
        int i = base + tid;
        int cl[CHK];
        int orig = 0;
        if (i < NNODES) {
            int s = i / HALF, np = i - s * HALF;
            const u8* cp = counts + ((size_t)(t * 2 + s) * CHK) * HALF + np;
#pragma unroll
            for (int c = 0; c < CHK; ++c) { cl[c] = cp[c * HALF]; orig += cl[c]; }
        }
        int v = orig;
#pragma unroll
        for (int off = 1; off < 64; off <<= 1) {
            int n = __shfl_up(v, off);
            if (lane >= off) v += n;
        }
        if (lane == 63) wsum[wid] = v;
        __syncthreads();
        if (wid == 0 && lane < 16) {
            int s = wsum[lane];
#pragma unroll
            for (int off = 1; off < 16; off <<= 1) {
                int n = __shfl_up(s, off);
                if (lane >= off) s += n;
            }
            wsum[lane] = s;
        }
        __syncthreads();
        int incl = v + (wid > 0 ? wsum[wid - 1] : 0) + carry_s;
        int excl = incl - orig;
        if (i < NNODES) {
            rowstart[t * RS_STRIDE + i] = excl;
            dinv[t * NNODES + i] = rsqrtf((float)(orig + 1));
            int s = i / HALF, np = i - s * HALF;
            int* op = chunkoff + ((size_t)(t * 2 + s) * CHK) * HALF + np;
            int run = excl;
#pragma unroll
            for (int c = 0; c < CHK; ++c) { op[c * HALF] = run; run += cl[c]; }
        }
        __syncthreads();
        if (tid == 0) carry_s += wsum[15];
        __syncthreads();
    }
    if (tid == 0) rowstart[t * RS_STRIDE + NNODES] = carry_s;
}

__global__ void __launch_bounds__(1024) fill2(const int* __restrict__ edges,
        const u8* __restrict__ rank, const int* __restrict__ chunkoff,
        int* __restrict__ col) {
    __shared__ int loff[HALF];
    int c = blockIdx.x & 15;
    int rest = blockIdx.x >> 4;
    int s = rest & 1, t = rest >> 1;
    const int* op = chunkoff + (((size_t)(t * 2 + s) * CHK + c) * HALF);
    for (int i = threadIdx.x; i < HALF; i += 1024) loff[i] = op[i];
    __syncthreads();
    int lo = s * HALF;
    const int* sb = edges + (size_t)t * 2 * NEDGES;
    const int* db = sb + NEDGES;
    const u8* rk = rank + (size_t)t * NEDGES;
    int* ct = col + (size_t)t * NEDGES;
    int per = NEDGES / CHK;
    int e0 = c * per, e1 = e0 + per;
    for (int i = e0 + (int)threadIdx.x; i < e1; i += 1024) {
        int d = db[i] - lo;
        if ((unsigned)d < HALF)
            ct[loff[d] + (int)rk[i]] = sb[i];
    }
}

// ---------------- merged conversions + fp16 LSTM weights (verified R17) ----------------
// lw: [m][k 0..127][1024] u32; (m,k,r) packs fp16 {W[r][2k], W[r][2k+1]}.
// m: 0=Wih0 1=Whh0 2=Wih1 3=Whh1.

__global__ void __launch_bounds__(256) convall(
        const float* __restrict__ x, const float* __restrict__ dinv, u8* __restrict__ xb,
        const float* __restrict__ W1, u16* __restrict__ W1t,
        const float* __restrict__ W2, u16* __restrict__ W2t,
        const float* __restrict__ Wih0, const float* __restrict__ Whh0,
        const float* __restrict__ Wih1, const float* __restrict__ Whh1,
        u32* __restrict__ lw,
        float* __restrict__ pooled, u64* __restrict__ hbuf) {
    int bid = blockIdx.x;
    int tid = threadIdx.x;
    if (bid < 30000) {
        int idx = bid * 256 + tid;
        int row = idx >> 5, q = idx & 31;
        float dn = dinv[row];
        float4 v = *(const float4*)&x[(size_t)row * FIN + q * 4];
        int p = __builtin_amdgcn_cvt_pk_fp8_f32(dn * v.x, dn * v.y, 0, false);
        p = __builtin_amdgcn_cvt_pk_fp8_f32(dn * v.z, dn * v.w, p, true);
        ((u32*)xb)[(size_t)row * 32 + q] = (u32)p;
    } else if (bid < 30128) {
        int idx = (bid - 30000) * 256 + tid;
        int n = idx / FIN, k = idx - n * FIN;
        W1t[idx] = f2bf(W1[k * HG + n]);
    } else if (bid < 30384) {
        int idx = (bid - 30128) * 256 + tid;
        int n = idx >> 8, k = idx & 255;
        W2t[idx] = f2bf(W2[k * HG + n]);
    } else if (bid == 30384) {
        for (int i = tid; i < T_STEPS * HG; i += 256) pooled[i] = 0.f;
        for (int i = tid; i < 512; i += 256) hbuf[i] = 0ull;
    } else {
        int idx = bid - 30385;                 // 0..4095: (m, row)
        int m = idx >> 10, r = idx & 1023;
        const float* src = (m == 0) ? Wih0 : (m == 1) ? Whh0 : (m == 2) ? Wih1 : Whh1;
        if (tid < 128) {
            float2 w2 = *(const float2*)&src[(size_t)r * HG + tid * 2];
            lw[((size_t)m * 128 + tid) * 1024 + r] =
                (u32)f2h(w2.x) | ((u32)f2h(w2.y) << 16);
        }
    }
}

// ---------------- pull aggregation, fp8 payload (verified R12-R17) ----------------

__global__ void __launch_bounds__(256) agg128(const u8* __restrict__ xb,
        const int* __restrict__ rowstart, const int* __restrict__ col,
        const float* __restrict__ dinv, u16* __restrict__ out) {
    int glob = (blockIdx.x << 2) + (threadIdx.x >> 6);
    int lane = threadIdx.x & 63;
    int t = glob / MPAD, node = glob - t * MPAD;
    u16* orow = out + ((size_t)glob) * FIN;
    if (node >= NNODES) { *(u32*)&orow[lane << 1] = 0; return; }
    const u8* xt = xb + (size_t)t * NNODES * FIN;
    const int* cb = col + (size_t)t * NEDGES;
    int o2 = lane << 1;
    u32 pv = *(const u16*)&xt[(size_t)node * FIN + o2];
    v2f f = __builtin_amdgcn_cvt_pk_f32_fp8((int)pv, false);
    float ax = f[0], ay = f[1];
    int s0 = rowstart[t * RS_STRIDE + node], s1 = rowstart[t * RS_STRIDE + node + 1];
    int e = s0;
    for (; e + 16 <= s1; e += 16) {
        int ix[16]; u32 rv[16];
#pragma unroll
        for (int j = 0; j < 16; ++j) ix[j] = cb[e + j];
#pragma unroll
        for (int j = 0; j < 16; ++j) rv[j] = *(const u16*)&xt[(size_t)ix[j] * FIN + o2];
#pragma unroll
        for (int j = 0; j < 16; ++j) {
            v2f g = __builtin_amdgcn_cvt_pk_f32_fp8((int)rv[j], false);
            ax += g[0]; ay += g[1];
        }
    }
    for (; e + 4 <= s1; e += 4) {
        int ix[4]; u32 rv[4];
#pragma unroll
        for (int j = 0; j < 4; ++j) ix[j] = cb[e + j];
#pragma unroll
        for (int j = 0; j < 4; ++j) rv[j] = *(const u16*)&xt[(size_t)ix[j] * FIN + o2];
#pragma unroll
        for (int j = 0; j < 4; ++j) {
            v2f g = __builtin_amdgcn_cvt_pk_f32_fp8((int)rv[j], false);
            ax += g[0]; ay += g[1];
        }
    }
    for (; e < s1; ++e) {
        u32 rv = *(const u16*)&xt[(size_t)cb[e] * FIN + o2];
        v2f g = __builtin_amdgcn_cvt_pk_f32_fp8((int)rv, false);
        ax += g[0]; ay += g[1];
    }
    float dn = dinv[t * NNODES + node];
    u32 packed = (u32)f2bf(dn * ax) | ((u32)f2bf(dn * ay) << 16);
    *(u32*)&orow[o2] = packed;
}

__global__ void __launch_bounds__(256) agg256(const u8* __restrict__ xin,
        const int* __restrict__ rowstart, const int* __restrict__ col,
        const float* __restrict__ dinv, u16* __restrict__ out) {
    int glob = (blockIdx.x << 2) + (threadIdx.x >> 6);
    int lane = threadIdx.x & 63;
    int t = glob / MPAD, node = glob - t * MPAD;
    u16* orow = out + ((size_t)glob) * HG;
    if (node >= NNODES) { *(ushort4*)&orow[lane << 2] = make_ushort4(0, 0, 0, 0); return; }
    const u8* xt = xin + (size_t)t * MPAD * HG;
    const int* cb = col + (size_t)t * NEDGES;
    int o4 = lane << 2;
    u32 pv = *(const u32*)&xt[(size_t)node * HG + o4];
    v2f f01 = __builtin_amdgcn_cvt_pk_f32_fp8((int)pv, false);
    v2f f23 = __builtin_amdgcn_cvt_pk_f32_fp8((int)pv, true);
    float a0 = f01[0], a1 = f01[1], a2 = f23[0], a3 = f23[1];
    int s0 = rowstart[t * RS_STRIDE + node], s1 = rowstart[t * RS_STRIDE + node + 1];
    int e = s0;
    for (; e + 16 <= s1; e += 16) {
        int ix[16]; u32 rv[16];
#pragma unroll
        for (int j = 0; j < 16; ++j) ix[j] = cb[e + j];
#pragma unroll
        for (int j = 0; j < 16; ++j) rv[j] = *(const u32*)&xt[(size_t)ix[j] * HG + o4];
#pragma unroll
        for (int j = 0; j < 16; ++j) {
            v2f g01 = __builtin_amdgcn_cvt_pk_f32_fp8((int)rv[j], false);
            v2f g23 = __builtin_amdgcn_cvt_pk_f32_fp8((int)rv[j], true);
            a0 += g01[0]; a1 += g01[1]; a2 += g23[0]; a3 += g23[1];
        }
    }
    for (; e + 4 <= s1; e += 4) {
        int ix[4]; u32 rv[4];
#pragma unroll
        for (int j = 0; j < 4; ++j) ix[j] = cb[e + j];
#pragma unroll
        for (int j = 0; j < 4; ++j) rv[j] = *(const u32*)&xt[(size_t)ix[j] * HG + o4];
#pragma unroll
        for (int j = 0; j < 4; ++j) {
            v2f g01 = __builtin_amdgcn_cvt_pk_f32_fp8((int)rv[j], false);
            v2f g23 = __builtin_amdgcn_cvt_pk_f32_fp8((int)rv[j], true);
            a0 += g01[0]; a1 += g01[1]; a2 += g23[0]; a3 += g23[1];
        }
    }
    for (; e < s1; ++e) {
        u32 rv = *(const u32*)&xt[(size_t)cb[e] * HG + o4];
        v2f g01 = __builtin_amdgcn_cvt_pk_f32_fp8((int)rv, false);
        v2f g23 = __builtin_amdgcn_cvt_pk_f32_fp8((int)rv, true);
        a0 += g01[0]; a1 += g01[1]; a2 += g23[0]; a3 += g23[1];
    }
    float dn = dinv[t * NNODES + node];
    ushort4 o;
    o.x = f2bf(dn * a0); o.y = f2bf(dn * a1); o.z = f2bf(dn * a2); o.w = f2bf(dn * a3);
    *(ushort4*)&orow[o4] = o;
}

// ---------------- bf16 MFMA GEMM, 64M x 256N tile (verified R7-R17) ----------------

template <int K, bool POOL>
__global__ __launch_bounds__(256) void gemm_bf16(
        const u16* __restrict__ A, const u16* __restrict__ Bt,
        const float* __restrict__ bias, const float* __restrict__ dscale,
        u8* __restrict__ C, float* __restrict__ pool) {
    __shared__ u16 As[64 * 64];
    __shared__ u16 Bs[256 * 64];
    __shared__ float csum[HG];
    int tid = threadIdx.x;
    int bm = blockIdx.x * 64;
    int t8 = tid >> 3, sl = tid & 7;
    int lane = tid & 63, w = tid >> 6;
    int r0 = lane & 15, gq = lane >> 4;
    int tblk = blockIdx.x / 313;

    f32x4 acc[4][4] = {};

    for (int k0 = 0; k0 < K; k0 += 64) {
#pragma unroll
        for (int i = 0; i < 2; ++i) {
            int r = i * 32 + t8;
            int ch = sl ^ (r & 7);
            gload16(A + (size_t)(bm + r) * K + k0 + ch * 8, &As[i * 2048 + tid * 8]);
        }
#pragma unroll
        for (int i = 0; i < 8; ++i) {
            int r = i * 32 + t8;
            int ch = sl ^ (r & 7);
            gload16(Bt + (size_t)r * K + k0 + ch * 8, &Bs[i * 2048 + tid * 8]);
        }
        __syncthreads();
#pragma unroll
        for (int kk = 0; kk < 2; ++kk) {
            bf16x8 a[4], b[4];
#pragma unroll
            for (int mi = 0; mi < 4; ++mi) {
                int R = mi * 16 + r0;
                int s = (kk * 4 + gq) ^ (R & 7);
                a[mi] = *(const bf16x8*)&As[R * 64 + s * 8];
            }
#pragma unroll
            for (int ni = 0; ni < 4; ++ni) {
                int R = w * 64 + ni * 16 + r0;
                int s = (kk * 4 + gq) ^ (R & 7);
                b[ni] = *(const bf16x8*)&Bs[R * 64 + s * 8];
            }
#pragma unroll
            for (int mi = 0; mi < 4; ++mi)
#pragma unroll
                for (int ni = 0; ni < 4; ++ni)
                    acc[mi][ni] = __builtin_amdgcn_mfma_f32_16x16x32_bf16(
                        a[mi], b[ni], acc[mi][ni], 0, 0, 0);
        }
        __syncthreads();
    }

    if (!POOL) {
#pragma unroll
        for (int ni = 0; ni < 4; ++ni) {
            int colg = w * 64 + ni * 16 + r0;
            float b = bias[colg];
#pragma unroll
            for (int mi = 0; mi < 4; ++mi) {
                int rbase = bm + mi * 16 + gq * 4;
#pragma unroll
                for (int q = 0; q < 4; ++q) {
                    int row = rbase + q;
                    int rloc = row - tblk * MPAD;
                    float sc = (rloc < NNODES) ? dscale[tblk * NNODES + rloc] : 0.f;
                    float val = sc * fmaxf(acc[mi][ni][q] + b, 0.f);
                    int p = __builtin_amdgcn_cvt_pk_fp8_f32(val, val, 0, false);
                    C[(size_t)row * HG + colg] = (u8)(p & 0xff);
                }
            }
        }
    } else {
        csum[tid] = 0.f;
        __syncthreads();
#pragma unroll
        for (int ni = 0; ni < 4; ++ni) {
            int colg = w * 64 + ni * 16 + r0;
            float b = bias[colg];
            float s = 0.f;
#pragma unroll
            for (int mi = 0; mi < 4; ++mi) {
                int rbase = bm + mi * 16 + gq * 4;
#pragma unroll
                for (int q = 0; q < 4; ++q) {
                    int row = rbase + q;
                    int rloc = row - tblk * MPAD;
                    if (rloc < NNODES) s += fmaxf(acc[mi][ni][q] + b, 0.f);
                }
            }
            atomicAdd(&csum[colg], s);
        }
        __syncthreads();
        atomicAdd(&pool[tblk * HG + tid], csum[tid]);
    }
}

// ---------------- 2-block LSTM: 2 gate rows/thread (256 VGPR weights), 1 peer ----------------
// Block b owns units [b*128, b*128+128). Thread: unit u = b*128+(tid&127), gates
// g0=(tid>>7)*2, g1=g0+1 -> rows r0=g0*256+u, r1=g1*256+u. Tagged-payload exchange
// (verified protocol R10-R17): u64 = tag<<32 | f32(h); 128 slots/block/parity.
// Poll population 128/block (threads 0..127), one remote block. 2 barriers/step.

__global__ void __launch_bounds__(256, 1) lstm2d(
        const float* __restrict__ pooled, const u32* __restrict__ lw,
        const float* __restrict__ bih0, const float* __restrict__ bhh0,
        const float* __restrict__ bih1, const float* __restrict__ bhh1,
        const float* __restrict__ Wlin, const float* __restrict__ blin,
        u64* hbuf, float* __restrict__ out) {
    __shared__ float xs[T_STEPS][HG];
    __shared__ float hseqL[T_STEPS][HG];
    __shared__ float hl[HG];
    __shared__ float garr[4][128];
    int tid = threadIdx.x;
    int b = blockIdx.x, ob = 1 - b;
    int ul = tid & 127;
    int u = b * 128 + ul;
    int g0 = (tid >> 7) * 2;
    int r0 = g0 * 256 + u, r1 = (g0 + 1) * 256 + u;

    for (int i = tid; i < T_STEPS * HG; i += 256)
        ((float*)xs)[i] = pooled[i] * (1.f / (float)NNODES);
    __syncthreads();

    u32 wregA[128], wregB[128];
    float preA[T_STEPS], preB[T_STEPS];

    // ---- layer-0 input projections for rows r0, r1 ----
    {
        const u32* wpA = lw + r0;
        const u32* wpB = lw + r1;
#pragma unroll
        for (int k = 0; k < 128; ++k) { wregA[k] = wpA[(size_t)k * 1024]; wregB[k] = wpB[(size_t)k * 1024]; }
#pragma unroll
        for (int t = 0; t < T_STEPS; ++t) { preA[t] = 0.f; preB[t] = 0.f; }
        for (int k = 0; k < 128; ++k) {
            u32 wa = wregA[k], wb = wregB[k];
            float a0 = h2f((u16)wa), a1 = h2f((u16)(wa >> 16));
            float b0 = h2f((u16)wb), b1 = h2f((u16)(wb >> 16));
#pragma unroll
            for (int t = 0; t < T_STEPS; ++t) {
                float x0 = xs[t][2 * k], x1 = xs[t][2 * k + 1];
                preA[t] += a0 * x0 + a1 * x1;
                preB[t] += b0 * x0 + b1 * x1;
            }
        }
        float bbA = bih0[r0] + bhh0[r0];
        float bbB = bih0[r1] + bhh0[r1];
#pragma unroll
        for (int t = 0; t < T_STEPS; ++t) { preA[t] += bbA; preB[t] += bbB; }
    }

    float c = 0.f;
    for (int layer = 0; layer < 2; ++layer) {
        {   // recurrent weights for this layer (m = 1 or 3)
            const u32* wpA = lw + (size_t)((layer ? 3 : 1) * 128) * 1024 + r0;
            const u32* wpB = lw + (size_t)((layer ? 3 : 1) * 128) * 1024 + r1;
#pragma unroll
            for (int k = 0; k < 128; ++k) { wregA[k] = wpA[(size_t)k * 1024]; wregB[k] = wpB[(size_t)k * 1024]; }
        }
        c = 0.f;
        hl[tid] = 0.f;
        if (tid < 256 - HG) { /* nop: HG==256 so all covered */ }
        __syncthreads();
        for (int t = 0; t < T_STEPS; ++t) {
            int s = layer * T_STEPS + t + 1;
            float acc0 = 0.f, acc1 = 0.f;
#pragma unroll
            for (int k = 0; k < 128; ++k) {
                u32 wa = wregA[k], wb = wregB[k];
                float2 hv = *(const float2*)&hl[k * 2];
                acc0 += h2f((u16)wa) * hv.x + h2f((u16)(wa >> 16)) * hv.y;
                acc1 += h2f((u16)wb) * hv.x + h2f((u16)(wb >> 16)) * hv.y;
            }
            garr[g0][ul]     = preA[t] + acc0;
            garr[g0 + 1][ul] = preB[t] + acc1;
            __syncthreads();                           // A: garr ready, hl reads done
            if (tid < 128) {
                float ig = sigm(garr[0][tid]);
                float fg = sigm(garr[1][tid]);
                float gg = tanhf(garr[2][tid]);
                float og = sigm(garr[3][tid]);
                c = fg * c + ig * gg;
                float hn = og * tanhf(c);
                hl[u] = hn;
                u32 hb; __builtin_memcpy(&hb, &hn, 4);
                u64 pk = ((u64)(u32)s << 32) | (u64)hb;
                __hip_atomic_store(&hbuf[(s & 1) * 256 + u], pk,
                                   __ATOMIC_RELAXED, __HIP_MEMORY_SCOPE_AGENT);
                // poll the single remote block's slot
                u64 v = __hip_atomic_load(&hbuf[(s & 1) * 256 + ob * 128 + tid],
                                          __ATOMIC_RELAXED, __HIP_MEMORY_SCOPE_AGENT);
                while ((u32)(v >> 32) != (u32)s) {
                    __builtin_amdgcn_s_sleep(1);
                    v = __hip_atomic_load(&hbuf[(s & 1) * 256 + ob * 128 + tid],
                                          __ATOMIC_RELAXED, __HIP_MEMORY_SCOPE_AGENT);
                }
                u32 lo = (u32)v;
                float hv; __builtin_memcpy(&hv, &lo, 4);
                hl[ob * 128 + tid] = hv;
            }
            __syncthreads();                           // C: hl complete
            if (layer == 0) hseqL[t][tid] = hl[tid];
        }
        if (layer == 0) {
            __syncthreads();
            // layer-1 input projection from hseqL (m=2 rows r0, r1)
            const u32* wpA = lw + (size_t)(2 * 128) * 1024 + r0;
            const u32* wpB = lw + (size_t)(2 * 128) * 1024 + r1;
#pragma unroll
            for (int t = 0; t < T_STEPS; ++t) { preA[t] = 0.f; preB[t] = 0.f; }
            for (int k = 0; k < 128; ++k) {
                u32 wa = wpA[(size_t)k * 1024], wb = wpB[(size_t)k * 1024];
                float a0 = h2f((u16)wa), a1 = h2f((u16)(wa >> 16));
                float b0 = h2f((u16)wb), b1 = h2f((u16)(wb >> 16));
#pragma unroll
                for (int t = 0; t < T_STEPS; ++t) {
                    float h0 = hseqL[t][2 * k], h1 = hseqL[t][2 * k + 1];
                    preA[t] += a0 * h0 + a1 * h1;
                    preB[t] += b0 * h0 + b1 * h1;
                }
            }
            float bbA = bih1[r0] + bhh1[r0];
            float bbB = bih1[r1] + bhh1[r1];
#pragma unroll
            for (int t = 0; t < T_STEPS; ++t) { preA[t] += bbA; preB[t] += bbB; }
            __syncthreads();
        }
    }

    if (b == 0 && tid < 8) {
        float s = blin[tid];
        const float* wl = Wlin + tid * HG;
        for (int k = 0; k < HG; ++k) s += hl[k] * wl[k];
        out[tid] = s;
    }
}

// ---------------- orchestration ----------------

extern "C" void kernel_launch(void* const* d_in, const int* in_sizes, int n_in,
                              void* d_out, int out_size, void* d_ws, size_t ws_size,
                              hipStream_t stream) {
    const float* x    = (const float*)d_in[0];
    const int*   edges= (const int*)d_in[1];
    const float* W1   = (const float*)d_in[3];
    const float* b1   = (const float*)d_in[4];
    const float* W2   = (const float*)d_in[5];
    const float* b2   = (const float*)d_in[6];
    const float* Wih0 = (const float*)d_in[7];
    const float* Whh0 = (const float*)d_in[8];
    const float* bih0 = (const float*)d_in[9];
    const float* bhh0 = (const float*)d_in[10];
    const float* Wih1 = (const float*)d_in[11];
    const float* Whh1 = (const float*)d_in[12];
    const float* bih1 = (const float*)d_in[13];
    const float* bhh1 = (const float*)d_in[14];
    const float* Wlin = (const float*)d_in[15];
    const float* blin = (const float*)d_in[16];
    (void)in_sizes; (void)n_in; (void)out_size;

    char* p = (char*)d_ws;
    auto alloc = [&](size_t bytes) -> char* {
        char* q = p; p += (bytes + 255) & ~(size_t)255; return q;
    };
    int*   rowstart = (int*)  alloc(sizeof(int)   * T_STEPS * RS_STRIDE);
    float* dinv     = (float*)alloc(sizeof(float) * T_STEPS * NNODES);
    int*   col      = (int*)  alloc(sizeof(int)   * T_STEPS * NEDGES);
    u8*    rank     = (u8*)   alloc((size_t)T_STEPS * NEDGES);
    u8*    counts   = (u8*)   alloc((size_t)T_STEPS * 2 * CHK * HALF);
    int*   chunkoff = (int*)  alloc(sizeof(int)   * (size_t)T_STEPS * 2 * CHK * HALF);
    float* pooled   = (float*)alloc(sizeof(float) * T_STEPS * HG);
    u16*   W1t      = (u16*)  alloc(sizeof(u16)   * HG * FIN);
    u16*   W2t      = (u16*)  alloc(sizeof(u16)   * HG * HG);
    u32*   lw       = (u32*)  alloc(sizeof(u32)   * 4 * 128 * 1024);
    u64*   hbuf     = (u64*)  alloc(sizeof(u64)   * 2 * 256);
    size_t fixed_used = (size_t)(p - (char*)d_ws);

    const size_t xb_bytes  = (size_t)T_STEPS * NNODES * FIN;
    const size_t per_g     = (size_t)MPAD * HG * (1 + 2);
    const size_t slack     = 4096 * 16;
    static const int gopts[6] = {12, 6, 4, 3, 2, 1};
    int G = 1;
    for (int i = 0; i < 6; ++i)
        if (fixed_used + xb_bytes + per_g * gopts[i] + slack <= ws_size) { G = gopts[i]; break; }
    u8*  xb   = (u8*) alloc(xb_bytes);
    u8*  h1b  = (u8*) alloc((size_t)G * MPAD * HG);
    u16* aggu = (u16*)alloc(sizeof(u16) * (size_t)G * MPAD * HG);

    hist2<<<T_STEPS * 2 * CHK, 1024, 0, stream>>>(edges, rank, counts);
    scan2<<<T_STEPS, 1024, 0, stream>>>(counts, rowstart, dinv, chunkoff);
    fill2<<<T_STEPS * 2 * CHK, 1024, 0, stream>>>(edges, rank, chunkoff, col);
    convall<<<34481, 256, 0, stream>>>(x, dinv, xb, W1, W1t, W2, W2t,
                                       Wih0, Whh0, Wih1, Whh1, lw, pooled, hbuf);

    for (int g = 0; g < T_STEPS / G; ++g) {
        int t0 = g * G;
        const u8*    xbg = xb + (size_t)t0 * NNODES * FIN;
        const int*   rsg = rowstart + (size_t)t0 * RS_STRIDE;
        const int*   clg = col + (size_t)t0 * NEDGES;
        const float* dvg = dinv + (size_t)t0 * NNODES;
        int nagg = G * MPAD / 4;
        agg128<<<nagg, 256, 0, stream>>>(xbg, rsg, clg, dvg, aggu);
        gemm_bf16<FIN, false><<<G * 313, 256, 0, stream>>>(aggu, W1t, b1, dvg,
                h1b, nullptr);
        agg256<<<nagg, 256, 0, stream>>>(h1b, rsg, clg, dvg, aggu);
        gemm_bf16<HG, true><<<G * 313, 256, 0, stream>>>(aggu, W2t, b2, nullptr,
                nullptr, pooled + (size_t)t0 * HG);
    }
    lstm2d<<<2, 256, 0, stream>>>(pooled, lw, bih0, bhh0, bih1, bhh1, Wlin, blin,
                                  hbuf, (float*)d_out);
}

// Round 19
// 739.919 us; speedup vs baseline: 1.2901x; 1.2901x over previous
//
#include <hip/hip_runtime.h>
#include <hip/hip_bf16.h>
#include <math.h>

#define T_STEPS 12
#define NNODES  20000
#define NEDGES  320000
#define MPAD    20032
#define FIN     128
#define HG      256
#define RS_STRIDE 20032
#define CHK     16
#define HALF    10000

typedef unsigned short u16;
typedef unsigned int   u32;
typedef unsigned char  u8;
typedef unsigned long long u64;
using bf16x8 = __attribute__((ext_vector_type(8))) short;
using f32x4  = __attribute__((ext_vector_type(4))) float;
typedef float v2f __attribute__((ext_vector_type(2)));

__device__ __forceinline__ float bf2f(u16 u) {
    union { u32 i; float f; } v; v.i = ((u32)u) << 16; return v.f;
}
__device__ __forceinline__ u16 f2bf(float f) {
    union { float f; u32 i; } v; v.f = f;
    u32 r = v.i + 0x7fffu + ((v.i >> 16) & 1u);
    return (u16)(r >> 16);
}
__device__ __forceinline__ u16 f2h(float f) {
    _Float16 h = (_Float16)f; u16 u; __builtin_memcpy(&u, &h, 2); return u;
}
__device__ __forceinline__ float h2f(u16 u) {
    _Float16 h; __builtin_memcpy(&h, &u, 2); return (float)h;
}
__device__ __forceinline__ void gload16(const void* g, void* l) {
    __builtin_amdgcn_global_load_lds(
        (const __attribute__((address_space(1))) u32*)g,
        (__attribute__((address_space(3))) u32*)l, 16, 0, 0);
}
__device__ __forceinline__ float sigm(float x) { return 1.f / (1.f + expf(-x)); }

// ---------------- CSR build: rank-based counting sort (verified R16/R17) ----------------

__global__ void __launch_bounds__(1024) hist2(const int* __restrict__ edges,
        u8* __restrict__ rank, u8* __restrict__ counts) {
    __shared__ u32 lh[HALF];
    int c = blockIdx.x & 15;
    int rest = blockIdx.x >> 4;
    int s = rest & 1, t = rest >> 1;
    for (int i = threadIdx.x; i < HALF; i += 1024) lh[i] = 0;
    __syncthreads();
    int lo = s * HALF;
    const int* db = edges + (size_t)t * 2 * NEDGES + NEDGES;
    u8* rk = rank + (size_t)t * NEDGES;
    int per = NEDGES / CHK;
    int e0 = c * per, e1 = e0 + per;
    for (int i = e0 + (int)threadIdx.x; i < e1; i += 1024) {
        int d = db[i] - lo;
        if ((unsigned)d < HALF) {
            u32 r = atomicAdd(&lh[d], 1u);
            rk[i] = (u8)r;
        }
    }
    __syncthreads();
    u8* cnt = counts + (((size_t)(t * 2 + s) * CHK + c) * HALF);
    for (int i = threadIdx.x; i < HALF; i += 1024) cnt[i] = (u8)lh[i];
}

__global__ void __launch_bounds__(1024) scan2(const u8* __restrict__ counts,
        int* __restrict__ rowstart, float* __restrict__ dinv,
        int* __restrict__ chunkoff) {
    int t = blockIdx.x;
    int tid = threadIdx.x;
    int wid = tid >> 6, lane = tid & 63;
    __shared__ int wsum[16];
    __shared__ int carry_s;
    if (tid == 0) carry_s = 0;
    __syncthreads();
    for (int base = 0; base < NNODES; base += 1024) {
        int i = base + tid;
        int cl[CHK];
        int orig = 0;
        if (i < NNODES) {
            int s = i / HALF, np = i - s * HALF;
            const u8* cp = counts + ((size_t)(t * 2 + s) * CHK) * HALF + np;
#pragma unroll
            for (int c = 0; c < CHK; ++c) { cl[c] = cp[c * HALF]; orig += cl[c]; }
        }
        int v = orig;
#pragma unroll
        for (int off = 1; off < 64; off <<= 1) {
            int n = __shfl_up(v, off);
            if (lane >= off) v += n;
        }
        if (lane == 63) wsum[wid] = v;
        __syncthreads();
        if (wid == 0 && lane < 16) {
            int s = wsum[lane];
#pragma unroll
            for (int off = 1; off < 16; off <<= 1) {
                int n = __shfl_up(s, off);
                if (lane >= off) s += n;
            }
            wsum[lane] = s;
        }
        __syncthreads();
        int incl = v + (wid > 0 ? wsum[wid - 1] : 0) + carry_s;
        int excl = incl - orig;
        if (i < NNODES) {
            rowstart[t * RS_STRIDE + i] = excl;
            dinv[t * NNODES + i] = rsqrtf((float)(orig + 1));
            int s = i / HALF, np = i - s * HALF;
            int* op = chunkoff + ((size_t)(t * 2 + s) * CHK) * HALF + np;
            int run = excl;
#pragma unroll
            for (int c = 0; c < CHK; ++c) { op[c * HALF] = run; run += cl[c]; }
        }
        __syncthreads();
        if (tid == 0) carry_s += wsum[15];
        __syncthreads();
    }
    if (tid == 0) rowstart[t * RS_STRIDE + NNODES] = carry_s;
}

__global__ void __launch_bounds__(1024) fill2(const int* __restrict__ edges,
        const u8* __restrict__ rank, const int* __restrict__ chunkoff,
        int* __restrict__ col) {
    __shared__ int loff[HALF];
    int c = blockIdx.x & 15;
    int rest = blockIdx.x >> 4;
    int s = rest & 1, t = rest >> 1;
    const int* op = chunkoff + (((size_t)(t * 2 + s) * CHK + c) * HALF);
    for (int i = threadIdx.x; i < HALF; i += 1024) loff[i] = op[i];
    __syncthreads();
    int lo = s * HALF;
    const int* sb = edges + (size_t)t * 2 * NEDGES;
    const int* db = sb + NEDGES;
    const u8* rk = rank + (size_t)t * NEDGES;
    int* ct = col + (size_t)t * NEDGES;
    int per = NEDGES / CHK;
    int e0 = c * per, e1 = e0 + per;
    for (int i = e0 + (int)threadIdx.x; i < e1; i += 1024) {
        int d = db[i] - lo;
        if ((unsigned)d < HALF)
            ct[loff[d] + (int)rk[i]] = sb[i];
    }
}

// ---------------- merged conversions + fp16 LSTM weights (verified R17) ----------------
// lw: [m][k 0..127][1024] u32; (m,k,r) packs fp16 {W[r][2k], W[r][2k+1]}.
// m: 0=Wih0 1=Whh0 2=Wih1 3=Whh1.

__global__ void __launch_bounds__(256) convall(
        const float* __restrict__ x, const float* __restrict__ dinv, u8* __restrict__ xb,
        const float* __restrict__ W1, u16* __restrict__ W1t,
        const float* __restrict__ W2, u16* __restrict__ W2t,
        const float* __restrict__ Wih0, const float* __restrict__ Whh0,
        const float* __restrict__ Wih1, const float* __restrict__ Whh1,
        u32* __restrict__ lw,
        float* __restrict__ pooled, u64* __restrict__ hbuf) {
    int bid = blockIdx.x;
    int tid = threadIdx.x;
    if (bid < 30000) {
        int idx = bid * 256 + tid;
        int row = idx >> 5, q = idx & 31;
        float dn = dinv[row];
        float4 v = *(const float4*)&x[(size_t)row * FIN + q * 4];
        int p = __builtin_amdgcn_cvt_pk_fp8_f32(dn * v.x, dn * v.y, 0, false);
        p = __builtin_amdgcn_cvt_pk_fp8_f32(dn * v.z, dn * v.w, p, true);
        ((u32*)xb)[(size_t)row * 32 + q] = (u32)p;
    } else if (bid < 30128) {
        int idx = (bid - 30000) * 256 + tid;
        int n = idx / FIN, k = idx - n * FIN;
        W1t[idx] = f2bf(W1[k * HG + n]);
    } else if (bid < 30384) {
        int idx = (bid - 30128) * 256 + tid;
        int n = idx >> 8, k = idx & 255;
        W2t[idx] = f2bf(W2[k * HG + n]);
    } else if (bid == 30384) {
        for (int i = tid; i < T_STEPS * HG; i += 256) pooled[i] = 0.f;
        for (int i = tid; i < (T_STEPS + 2) * 256; i += 256) hbuf[i] = 0ull;
    } else {
        int idx = bid - 30385;                 // 0..4095: (m, row)
        int m = idx >> 10, r = idx & 1023;
        const float* src = (m == 0) ? Wih0 : (m == 1) ? Whh0 : (m == 2) ? Wih1 : Whh1;
        if (tid < 128) {
            float2 w2 = *(const float2*)&src[(size_t)r * HG + tid * 2];
            lw[((size_t)m * 128 + tid) * 1024 + r] =
                (u32)f2h(w2.x) | ((u32)f2h(w2.y) << 16);
        }
    }
}

// ---------------- pull aggregation, fp8 payload (verified R12-R17) ----------------

__global__ void __launch_bounds__(256) agg128(const u8* __restrict__ xb,
        const int* __restrict__ rowstart, const int* __restrict__ col,
        const float* __restrict__ dinv, u16* __restrict__ out) {
    int glob = (blockIdx.x << 2) + (threadIdx.x >> 6);
    int lane = threadIdx.x & 63;
    int t = glob / MPAD, node = glob - t * MPAD;
    u16* orow = out + ((size_t)glob) * FIN;
    if (node >= NNODES) { *(u32*)&orow[lane << 1] = 0; return; }
    const u8* xt = xb + (size_t)t * NNODES * FIN;
    const int* cb = col + (size_t)t * NEDGES;
    int o2 = lane << 1;
    u32 pv = *(const u16*)&xt[(size_t)node * FIN + o2];
    v2f f = __builtin_amdgcn_cvt_pk_f32_fp8((int)pv, false);
    float ax = f[0], ay = f[1];
    int s0 = rowstart[t * RS_STRIDE + node], s1 = rowstart[t * RS_STRIDE + node + 1];
    int e = s0;
    for (; e + 16 <= s1; e += 16) {
        int ix[16]; u32 rv[16];
#pragma unroll
        for (int j = 0; j < 16; ++j) ix[j] = cb[e + j];
#pragma unroll
        for (int j = 0; j < 16; ++j) rv[j] = *(const u16*)&xt[(size_t)ix[j] * FIN + o2];
#pragma unroll
        for (int j = 0; j < 16; ++j) {
            v2f g = __builtin_amdgcn_cvt_pk_f32_fp8((int)rv[j], false);
            ax += g[0]; ay += g[1];
        }
    }
    for (; e + 4 <= s1; e += 4) {
        int ix[4]; u32 rv[4];
#pragma unroll
        for (int j = 0; j < 4; ++j) ix[j] = cb[e + j];
#pragma unroll
        for (int j = 0; j < 4; ++j) rv[j] = *(const u16*)&xt[(size_t)ix[j] * FIN + o2];
#pragma unroll
        for (int j = 0; j < 4; ++j) {
            v2f g = __builtin_amdgcn_cvt_pk_f32_fp8((int)rv[j], false);
            ax += g[0]; ay += g[1];
        }
    }
    for (; e < s1; ++e) {
        u32 rv = *(const u16*)&xt[(size_t)cb[e] * FIN + o2];
        v2f g = __builtin_amdgcn_cvt_pk_f32_fp8((int)rv, false);
        ax += g[0]; ay += g[1];
    }
    float dn = dinv[t * NNODES + node];
    u32 packed = (u32)f2bf(dn * ax) | ((u32)f2bf(dn * ay) << 16);
    *(u32*)&orow[o2] = packed;
}

__global__ void __launch_bounds__(256) agg256(const u8* __restrict__ xin,
        const int* __restrict__ rowstart, const int* __restrict__ col,
        const float* __restrict__ dinv, u16* __restrict__ out) {
    int glob = (blockIdx.x << 2) + (threadIdx.x >> 6);
    int lane = threadIdx.x & 63;
    int t = glob / MPAD, node = glob - t * MPAD;
    u16* orow = out + ((size_t)glob) * HG;
    if (node >= NNODES) { *(ushort4*)&orow[lane << 2] = make_ushort4(0, 0, 0, 0); return; }
    const u8* xt = xin + (size_t)t * MPAD * HG;
    const int* cb = col + (size_t)t * NEDGES;
    int o4 = lane << 2;
    u32 pv = *(const u32*)&xt[(size_t)node * HG + o4];
    v2f f01 = __builtin_amdgcn_cvt_pk_f32_fp8((int)pv, false);
    v2f f23 = __builtin_amdgcn_cvt_pk_f32_fp8((int)pv, true);
    float a0 = f01[0], a1 = f01[1], a2 = f23[0], a3 = f23[1];
    int s0 = rowstart[t * RS_STRIDE + node], s1 = rowstart[t * RS_STRIDE + node + 1];
    int e = s0;
    for (; e + 16 <= s1; e += 16) {
        int ix[16]; u32 rv[16];
#pragma unroll
        for (int j = 0; j < 16; ++j) ix[j] = cb[e + j];
#pragma unroll
        for (int j = 0; j < 16; ++j) rv[j] = *(const u32*)&xt[(size_t)ix[j] * HG + o4];
#pragma unroll
        for (int j = 0; j < 16; ++j) {
            v2f g01 = __builtin_amdgcn_cvt_pk_f32_fp8((int)rv[j], false);
            v2f g23 = __builtin_amdgcn_cvt_pk_f32_fp8((int)rv[j], true);
            a0 += g01[0]; a1 += g01[1]; a2 += g23[0]; a3 += g23[1];
        }
    }
    for (; e + 4 <= s1; e += 4) {
        int ix[4]; u32 rv[4];
#pragma unroll
        for (int j = 0; j < 4; ++j) ix[j] = cb[e + j];
#pragma unroll
        for (int j = 0; j < 4; ++j) rv[j] = *(const u32*)&xt[(size_t)ix[j] * HG + o4];
#pragma unroll
        for (int j = 0; j < 4; ++j) {
            v2f g01 = __builtin_amdgcn_cvt_pk_f32_fp8((int)rv[j], false);
            v2f g23 = __builtin_amdgcn_cvt_pk_f32_fp8((int)rv[j], true);
            a0 += g01[0]; a1 += g01[1]; a2 += g23[0]; a3 += g23[1];
        }
    }
    for (; e < s1; ++e) {
        u32 rv = *(const u32*)&xt[(size_t)cb[e] * HG + o4];
        v2f g01 = __builtin_amdgcn_cvt_pk_f32_fp8((int)rv, false);
        v2f g23 = __builtin_amdgcn_cvt_pk_f32_fp8((int)rv, true);
        a0 += g01[0]; a1 += g01[1]; a2 += g23[0]; a3 += g23[1];
    }
    float dn = dinv[t * NNODES + node];
    ushort4 o;
    o.x = f2bf(dn * a0); o.y = f2bf(dn * a1); o.z = f2bf(dn * a2); o.w = f2bf(dn * a3);
    *(ushort4*)&orow[o4] = o;
}

// ---------------- bf16 MFMA GEMM, 64M x 256N tile (verified R7-R17) ----------------

template <int K, bool POOL>
__global__ __launch_bounds__(256) void gemm_bf16(
        const u16* __restrict__ A, const u16* __restrict__ Bt,
        const float* __restrict__ bias, const float* __restrict__ dscale,
        u8* __restrict__ C, float* __restrict__ pool) {
    __shared__ u16 As[64 * 64];
    __shared__ u16 Bs[256 * 64];
    __shared__ float csum[HG];
    int tid = threadIdx.x;
    int bm = blockIdx.x * 64;
    int t8 = tid >> 3, sl = tid & 7;
    int lane = tid & 63, w = tid >> 6;
    int r0 = lane & 15, gq = lane >> 4;
    int tblk = blockIdx.x / 313;

    f32x4 acc[4][4] = {};

    for (int k0 = 0; k0 < K; k0 += 64) {
#pragma unroll
        for (int i = 0; i < 2; ++i) {
            int r = i * 32 + t8;
            int ch = sl ^ (r & 7);
            gload16(A + (size_t)(bm + r) * K + k0 + ch * 8, &As[i * 2048 + tid * 8]);
        }
#pragma unroll
        for (int i = 0; i < 8; ++i) {
            int r = i * 32 + t8;
            int ch = sl ^ (r & 7);
            gload16(Bt + (size_t)r * K + k0 + ch * 8, &Bs[i * 2048 + tid * 8]);
        }
        __syncthreads();
#pragma unroll
        for (int kk = 0; kk < 2; ++kk) {
            bf16x8 a[4], b[4];
#pragma unroll
            for (int mi = 0; mi < 4; ++mi) {
                int R = mi * 16 + r0;
                int s = (kk * 4 + gq) ^ (R & 7);
                a[mi] = *(const bf16x8*)&As[R * 64 + s * 8];
            }
#pragma unroll
            for (int ni = 0; ni < 4; ++ni) {
                int R = w * 64 + ni * 16 + r0;
                int s = (kk * 4 + gq) ^ (R & 7);
                b[ni] = *(const bf16x8*)&Bs[R * 64 + s * 8];
            }
#pragma unroll
            for (int mi = 0; mi < 4; ++mi)
#pragma unroll
                for (int ni = 0; ni < 4; ++ni)
                    acc[mi][ni] = __builtin_amdgcn_mfma_f32_16x16x32_bf16(
                        a[mi], b[ni], acc[mi][ni], 0, 0, 0);
        }
        __syncthreads();
    }

    if (!POOL) {
#pragma unroll
        for (int ni = 0; ni < 4; ++ni) {
            int colg = w * 64 + ni * 16 + r0;
            float b = bias[colg];
#pragma unroll
            for (int mi = 0; mi < 4; ++mi) {
                int rbase = bm + mi * 16 + gq * 4;
#pragma unroll
                for (int q = 0; q < 4; ++q) {
                    int row = rbase + q;
                    int rloc = row - tblk * MPAD;
                    float sc = (rloc < NNODES) ? dscale[tblk * NNODES + rloc] : 0.f;
                    float val = sc * fmaxf(acc[mi][ni][q] + b, 0.f);
                    int p = __builtin_amdgcn_cvt_pk_fp8_f32(val, val, 0, false);
                    C[(size_t)row * HG + colg] = (u8)(p & 0xff);
                }
            }
        }
    } else {
        csum[tid] = 0.f;
        __syncthreads();
#pragma unroll
        for (int ni = 0; ni < 4; ++ni) {
            int colg = w * 64 + ni * 16 + r0;
            float b = bias[colg];
            float s = 0.f;
#pragma unroll
            for (int mi = 0; mi < 4; ++mi) {
                int rbase = bm + mi * 16 + gq * 4;
#pragma unroll
                for (int q = 0; q < 4; ++q) {
                    int row = rbase + q;
                    int rloc = row - tblk * MPAD;
                    if (rloc < NNODES) s += fmaxf(acc[mi][ni][q] + b, 0.f);
                }
            }
            atomicAdd(&csum[colg], s);
        }
        __syncthreads();
        atomicAdd(&pool[tblk * HG + tid], csum[tid]);
    }
}

// ---------------- layer-pipelined LSTM: 8 blocks = 2 groups x 4 ----------------
// Group 0 (bid<4): layer 0, identical structure to verified lstm4d layer-0 path;
//   publishes h0(t) into DEPTH-12 tagged buffer hbuf0[t][256] (no parity reuse ->
//   group 0 may run arbitrarily far ahead, no overwrite hazard).
// Group 1 (bid>=4): layer 1; Whh1 rows in 128 VGPRs; Wih1 rows (this block's 256)
//   in 128 KB LDS; per step: spin h0(t) (tag t+1), compute, exchange h1 among its
//   4 peers via parity buffer hbuf1 (proven R10-R17 protocol).
// Critical path: ~(T+1) exchanges instead of 2T.

__global__ void __launch_bounds__(256, 1) lstm_pipe(
        const float* __restrict__ pooled, const u32* __restrict__ lw,
        const float* __restrict__ bih0, const float* __restrict__ bhh0,
        const float* __restrict__ bih1, const float* __restrict__ bhh1,
        const float* __restrict__ Wlin, const float* __restrict__ blin,
        u64* hbuf, float* __restrict__ out) {
    __shared__ float xs[T_STEPS][HG];          // group 0
    __shared__ u32 wih[128][256];              // group 1 (128 KB)
    __shared__ float hl[HG];
    __shared__ float h0l[HG];
    __shared__ float garr[256];
    u64* hbuf0 = hbuf;                          // [12][256]
    u64* hbuf1 = hbuf + T_STEPS * 256;          // [2][256]
    int tid = threadIdx.x;
    int L = blockIdx.x >> 2;
    int b = blockIdx.x & 3;
    int lu = tid & 63;
    int unit = b * 64 + lu;
    int r = (tid >> 6) * 256 + unit;
    u32 wreg[128];

    if (L == 0) {
        for (int i = tid; i < T_STEPS * HG; i += 256)
            ((float*)xs)[i] = pooled[i] * (1.f / (float)NNODES);
        __syncthreads();
        float pre[T_STEPS];
        {
            const u32* wp = lw + r;             // m=0
#pragma unroll
            for (int t = 0; t < T_STEPS; ++t) pre[t] = 0.f;
            for (int k = 0; k < 128; ++k) {
                u32 pk = wp[(size_t)k * 1024];
                float w0 = h2f((u16)pk), w1 = h2f((u16)(pk >> 16));
#pragma unroll
                for (int t = 0; t < T_STEPS; ++t)
                    pre[t] += w0 * xs[t][2 * k] + w1 * xs[t][2 * k + 1];
            }
            float bb = bih0[r] + bhh0[r];
#pragma unroll
            for (int t = 0; t < T_STEPS; ++t) pre[t] += bb;
        }
        {
            const u32* wp = lw + (size_t)128 * 1024 + r;   // m=1 (Whh0)
#pragma unroll
            for (int k = 0; k < 128; ++k) wreg[k] = wp[(size_t)k * 1024];
        }
        float c = 0.f;
        hl[tid] = 0.f;
        __syncthreads();
        for (int t = 0; t < T_STEPS; ++t) {
            int s = t + 1;
            float acc = 0.f;
#pragma unroll
            for (int k = 0; k < 128; ++k) {
                u32 wv = wreg[k];
                float2 hv = *(const float2*)&hl[k * 2];
                acc += h2f((u16)wv) * hv.x + h2f((u16)(wv >> 16)) * hv.y;
            }
            garr[tid] = pre[t] + acc;
            __syncthreads();
            if (tid < 64) {
                float ig = sigm(garr[lu]);
                float fg = sigm(garr[64 + lu]);
                float gg = tanhf(garr[128 + lu]);
                float og = sigm(garr[192 + lu]);
                c = fg * c + ig * gg;
                float hn = og * tanhf(c);
                u32 hb; __builtin_memcpy(&hb, &hn, 4);
                u64 pk = ((u64)(u32)s << 32) | (u64)hb;
                __hip_atomic_store(&hbuf0[t * 256 + unit], pk,
                                   __ATOMIC_RELAXED, __HIP_MEMORY_SCOPE_AGENT);
            }
            if (t < T_STEPS - 1) {              // last h0 not needed by group 0
                u64 v;
                do {
                    v = __hip_atomic_load(&hbuf0[t * 256 + tid],
                                          __ATOMIC_RELAXED, __HIP_MEMORY_SCOPE_AGENT);
                } while ((u32)(v >> 32) != (u32)s);
                u32 lo = (u32)v;
                float hv; __builtin_memcpy(&hv, &lo, 4);
                __syncthreads();
                hl[tid] = hv;
                __syncthreads();
            }
        }
    } else {
        // load Wih1 rows (m=2) for this block's 256 gate rows into LDS
        for (int k = 0; k < 128; ++k)
            wih[k][tid] = lw[((size_t)(2 * 128) + k) * 1024 + r];
        {
            const u32* wp = lw + (size_t)(3 * 128) * 1024 + r;   // m=3 (Whh1)
#pragma unroll
            for (int k = 0; k < 128; ++k) wreg[k] = wp[(size_t)k * 1024];
        }
        float bias1 = bih1[r] + bhh1[r];
        float c = 0.f;
        hl[tid] = 0.f;
        __syncthreads();
        for (int t = 0; t < T_STEPS; ++t) {
            int s = t + 1;
            {   // wait for h0(t)
                u64 v;
                do {
                    v = __hip_atomic_load(&hbuf0[t * 256 + tid],
                                          __ATOMIC_RELAXED, __HIP_MEMORY_SCOPE_AGENT);
                } while ((u32)(v >> 32) != (u32)s);
                u32 lo = (u32)v;
                float hv; __builtin_memcpy(&hv, &lo, 4);
                h0l[tid] = hv;
            }
            __syncthreads();
            float acc = 0.f;
#pragma unroll
            for (int k = 0; k < 128; ++k) {
                u32 wi = wih[k][tid];
                u32 wh = wreg[k];
                float2 h0v = *(const float2*)&h0l[k * 2];
                float2 h1v = *(const float2*)&hl[k * 2];
                acc += h2f((u16)wi) * h0v.x + h2f((u16)(wi >> 16)) * h0v.y
                     + h2f((u16)wh) * h1v.x + h2f((u16)(wh >> 16)) * h1v.y;
            }
            garr[tid] = acc + bias1;
            __syncthreads();
            if (tid < 64) {
                float ig = sigm(garr[lu]);
                float fg = sigm(garr[64 + lu]);
                float gg = tanhf(garr[128 + lu]);
                float og = sigm(garr[192 + lu]);
                c = fg * c + ig * gg;
                float hn = og * tanhf(c);
                u32 hb; __builtin_memcpy(&hb, &hn, 4);
                u64 pk = ((u64)(u32)s << 32) | (u64)hb;
                __hip_atomic_store(&hbuf1[(s & 1) * 256 + unit], pk,
                                   __ATOMIC_RELAXED, __HIP_MEMORY_SCOPE_AGENT);
            }
            {   // exchange h1 among group-1 peers (parity, proven lockstep-safe)
                u64 v;
                do {
                    v = __hip_atomic_load(&hbuf1[(s & 1) * 256 + tid],
                                          __ATOMIC_RELAXED, __HIP_MEMORY_SCOPE_AGENT);
                } while ((u32)(v >> 32) != (u32)s);
                u32 lo = (u32)v;
                float hv; __builtin_memcpy(&hv, &lo, 4);
                __syncthreads();
                hl[tid] = hv;
                __syncthreads();
            }
        }
        if (b == 0 && tid < 8) {
            float sum = blin[tid];
            const float* wl = Wlin + tid * HG;
            for (int k = 0; k < HG; ++k) sum += hl[k] * wl[k];
            out[tid] = sum;
        }
    }
}

// ---------------- orchestration ----------------

extern "C" void kernel_launch(void* const* d_in, const int* in_sizes, int n_in,
                              void* d_out, int out_size, void* d_ws, size_t ws_size,
                              hipStream_t stream) {
    const float* x    = (const float*)d_in[0];
    const int*   edges= (const int*)d_in[1];
    const float* W1   = (const float*)d_in[3];
    const float* b1   = (const float*)d_in[4];
    const float* W2   = (const float*)d_in[5];
    const float* b2   = (const float*)d_in[6];
    const float* Wih0 = (const float*)d_in[7];
    const float* Whh0 = (const float*)d_in[8];
    const float* bih0 = (const float*)d_in[9];
    const float* bhh0 = (const float*)d_in[10];
    const float* Wih1 = (const float*)d_in[11];
    const float* Whh1 = (const float*)d_in[12];
    const float* bih1 = (const float*)d_in[13];
    const float* bhh1 = (const float*)d_in[14];
    const float* Wlin = (const float*)d_in[15];
    const float* blin = (const float*)d_in[16];
    (void)in_sizes; (void)n_in; (void)out_size;

    char* p = (char*)d_ws;
    auto alloc = [&](size_t bytes) -> char* {
        char* q = p; p += (bytes + 255) & ~(size_t)255; return q;
    };
    int*   rowstart = (int*)  alloc(sizeof(int)   * T_STEPS * RS_STRIDE);
    float* dinv     = (float*)alloc(sizeof(float) * T_STEPS * NNODES);
    int*   col      = (int*)  alloc(sizeof(int)   * T_STEPS * NEDGES);
    u8*    rank     = (u8*)   alloc((size_t)T_STEPS * NEDGES);
    u8*    counts   = (u8*)   alloc((size_t)T_STEPS * 2 * CHK * HALF);
    int*   chunkoff = (int*)  alloc(sizeof(int)   * (size_t)T_STEPS * 2 * CHK * HALF);
    float* pooled   = (float*)alloc(sizeof(float) * T_STEPS * HG);
    u16*   W1t      = (u16*)  alloc(sizeof(u16)   * HG * FIN);
    u16*   W2t      = (u16*)  alloc(sizeof(u16)   * HG * HG);
    u32*   lw       = (u32*)  alloc(sizeof(u32)   * 4 * 128 * 1024);
    u64*   hbuf     = (u64*)  alloc(sizeof(u64)   * (T_STEPS + 2) * 256);
    size_t fixed_used = (size_t)(p - (char*)d_ws);

    const size_t xb_bytes  = (size_t)T_STEPS * NNODES * FIN;
    const size_t per_g     = (size_t)MPAD * HG * (1 + 2);
    const size_t slack     = 4096 * 16;
    static const int gopts[6] = {12, 6, 4, 3, 2, 1};
    int G = 1;
    for (int i = 0; i < 6; ++i)
        if (fixed_used + xb_bytes + per_g * gopts[i] + slack <= ws_size) { G = gopts[i]; break; }
    u8*  xb   = (u8*) alloc(xb_bytes);
    u8*  h1b  = (u8*) alloc((size_t)G * MPAD * HG);
    u16* aggu = (u16*)alloc(sizeof(u16) * (size_t)G * MPAD * HG);

    hist2<<<T_STEPS * 2 * CHK, 1024, 0, stream>>>(edges, rank, counts);
    scan2<<<T_STEPS, 1024, 0, stream>>>(counts, rowstart, dinv, chunkoff);
    fill2<<<T_STEPS * 2 * CHK, 1024, 0, stream>>>(edges, rank, chunkoff, col);
    convall<<<34481, 256, 0, stream>>>(x, dinv, xb, W1, W1t, W2, W2t,
                                       Wih0, Whh0, Wih1, Whh1, lw, pooled, hbuf);

    for (int g = 0; g < T_STEPS / G; ++g) {
        int t0 = g * G;
        const u8*    xbg = xb + (size_t)t0 * NNODES * FIN;
        const int*   rsg = rowstart + (size_t)t0 * RS_STRIDE;
        const int*   clg = col + (size_t)t0 * NEDGES;
        const float* dvg = dinv + (size_t)t0 * NNODES;
        int nagg = G * MPAD / 4;
        agg128<<<nagg, 256, 0, stream>>>(xbg, rsg, clg, dvg, aggu);
        gemm_bf16<FIN, false><<<G * 313, 256, 0, stream>>>(aggu, W1t, b1, dvg,
                h1b, nullptr);
        agg256<<<nagg, 256, 0, stream>>>(h1b, rsg, clg, dvg, aggu);
        gemm_bf16<HG, true><<<G * 313, 256, 0, stream>>>(aggu, W2t, b2, nullptr,
                nullptr, pooled + (size_t)t0 * HG);
    }
    lstm_pipe<<<8, 256, 0, stream>>>(pooled, lw, bih0, bhh0, bih1, bhh1, Wlin, blin,
                                     hbuf, (float*)d_out);
}